// Round 1
// baseline (226.087 us; speedup 1.0000x reference)
//
#include <hip/hip_runtime.h>
#include <hip/hip_bf16.h>
#include <stdint.h>

typedef __bf16 bf16_t;
typedef float floatx4 __attribute__((ext_vector_type(4)));
typedef __bf16 bf16x8 __attribute__((ext_vector_type(8)));
typedef __bf16 bf16x4 __attribute__((ext_vector_type(4)));

// Problem constants
#define NB 4
#define NN 2048
#define DD 512
#define NH 8
#define DHD 64
#define BH (NB*NH)      // 32
#define MROWS (NB*NN)   // 8192
#define OCOLS (3*NH*DHD) // 1536

// -------------------- async global->LDS (16B) --------------------
__device__ __forceinline__ void gl2lds16(const bf16_t* g, bf16_t* l) {
    __builtin_amdgcn_global_load_lds(
        (const __attribute__((address_space(1))) unsigned int*)g,
        (__attribute__((address_space(3))) unsigned int*)l,
        16, 0, 0);
}

// -------------------- fp32 -> bf16 convert --------------------
__global__ __launch_bounds__(256) void convert_kernel(const float* __restrict__ in,
                                                      bf16_t* __restrict__ out, int n4) {
    int i = blockIdx.x * 256 + threadIdx.x;
    if (i < n4) {
        float4 v = ((const float4*)in)[i];
        bf16x4 o;
        o.x = (bf16_t)v.x; o.y = (bf16_t)v.y; o.z = (bf16_t)v.z; o.w = (bf16_t)v.w;
        ((bf16x4*)out)[i] = o;
    }
}

// -------------------- QKV projection GEMM (gemm_bt) --------------------
// C[m][o] = sum_k X[m][k] * W[o][k];  scatter epilogue into Q(scaled)/K/[Vt transposed]
__global__ __launch_bounds__(256) void qkv_gemm(const bf16_t* __restrict__ X,   // [8192][512]
                                                const bf16_t* __restrict__ W,   // [1536][512]
                                                bf16_t* __restrict__ Q,         // [32][2048][64] (pre-scaled)
                                                bf16_t* __restrict__ K,         // [32][2048][64]
                                                bf16_t* __restrict__ Vt)        // [32][64][2048]
{
    __shared__ bf16_t As[128 * 64];
    __shared__ bf16_t Bs[128 * 64];

    const int tid  = threadIdx.x;
    const int wave = tid >> 6;
    const int lane = tid & 63;
    const int quad = lane >> 4;
    const int lrow = lane & 15;
    const int bm0 = blockIdx.x * 128;
    const int bn0 = blockIdx.y * 128;
    const int mw = (wave >> 1) * 64;
    const int nw = (wave & 1) * 64;
    const int wbase = tid & 192;   // wave*64, wave-uniform

    floatx4 acc[4][4];
#pragma unroll
    for (int i = 0; i < 4; i++)
#pragma unroll
        for (int j = 0; j < 4; j++) acc[i][j] = (floatx4)0.0f;

#pragma unroll 1
    for (int kb = 0; kb < 8; ++kb) {
        const int k0 = kb * 64;
        __syncthreads();
        // stage A tile [128][64] and B tile [128][64]: 1024 16B-chunks each
#pragma unroll
        for (int r = 0; r < 4; ++r) {
            int c = r * 256 + tid;            // per-lane chunk
            int row = c >> 3, kc = c & 7;
            gl2lds16(X + (size_t)(bm0 + row) * 512 + k0 + kc * 8,
                     As + (size_t)(r * 256 + wbase) * 8);
        }
#pragma unroll
        for (int r = 0; r < 4; ++r) {
            int c = r * 256 + tid;
            int row = c >> 3, kc = c & 7;
            gl2lds16(W + (size_t)(bn0 + row) * 512 + k0 + kc * 8,
                     Bs + (size_t)(r * 256 + wbase) * 8);
        }
        __syncthreads();
#pragma unroll
        for (int ks = 0; ks < 2; ++ks) {
            bf16x8 af[4], bfr[4];
#pragma unroll
            for (int mi = 0; mi < 4; mi++)
                af[mi] = *(const bf16x8*)(As + (mw + mi * 16 + lrow) * 64 + ks * 32 + quad * 8);
#pragma unroll
            for (int ni = 0; ni < 4; ni++)
                bfr[ni] = *(const bf16x8*)(Bs + (nw + ni * 16 + lrow) * 64 + ks * 32 + quad * 8);
#pragma unroll
            for (int mi = 0; mi < 4; mi++)
#pragma unroll
                for (int ni = 0; ni < 4; ni++)
                    acc[mi][ni] = __builtin_amdgcn_mfma_f32_16x16x32_bf16(af[mi], bfr[ni], acc[mi][ni], 0, 0, 0);
        }
    }

    // epilogue: C/D layout col=lane&15, row=quad*4+reg  [verified m89]
#pragma unroll
    for (int mi = 0; mi < 4; mi++) {
        int mbase = bm0 + mw + mi * 16 + quad * 4;
#pragma unroll
        for (int ni = 0; ni < 4; ni++) {
            int o = bn0 + nw + ni * 16 + lrow;
            int s  = o >> 9;
            int h  = (o >> 6) & 7;
            int dh = o & 63;
#pragma unroll
            for (int r = 0; r < 4; r++) {
                int mm = mbase + r;
                int b = mm >> 11, n = mm & 2047;
                int bh = b * 8 + h;
                float v = acc[mi][ni][r];
                if (s == 0)      Q[((size_t)bh * 2048 + n) * 64 + dh] = (bf16_t)(v * 0.125f);
                else if (s == 1) K[((size_t)bh * 2048 + n) * 64 + dh] = (bf16_t)v;
                else             Vt[((size_t)bh * 64 + dh) * 2048 + n] = (bf16_t)v;
            }
        }
    }
}

// -------------------- flash attention --------------------
#define KP 72   // LDS pitch (bf16 elems): 64+8 -> 2-way bank aliasing only (free, m136)

__global__ __launch_bounds__(256) void flash_attn(const bf16_t* __restrict__ Q,   // [32][2048][64], pre-scaled
                                                  const bf16_t* __restrict__ K,   // [32][2048][64]
                                                  const bf16_t* __restrict__ Vt,  // [32][64][2048]
                                                  float* __restrict__ Out)        // [4][2048][512]
{
    __shared__ bf16_t Ks[64 * KP];
    __shared__ bf16_t Vs[64 * KP];
    __shared__ bf16_t Ps[4][16 * KP];

    const int tid  = threadIdx.x;
    const int wave = tid >> 6;
    const int lane = tid & 63;
    const int quad = lane >> 4;
    const int c    = lane & 15;
    const int qt = blockIdx.x;
    const int bh = blockIdx.y;
    const int b = bh >> 3, h = bh & 7;

    // Q fragments (A-operand: m=lane&15, k=quad*8+j), with shifted-query source row
    int qg  = qt * 64 + wave * 16 + c;
    int src = (qg == 0) ? 0 : qg - 1;
    const bf16_t* qbase = Q + ((size_t)bh * 2048 + src) * 64;
    bf16x8 qf0 = *(const bf16x8*)(qbase + quad * 8);
    bf16x8 qf1 = *(const bf16x8*)(qbase + 32 + quad * 8);

    floatx4 o[4];
#pragma unroll
    for (int i = 0; i < 4; i++) o[i] = (floatx4)0.0f;
    float mrow[4], lrow[4];
#pragma unroll
    for (int r = 0; r < 4; r++) { mrow[r] = -1e30f; lrow[r] = 0.0f; }

    const int srow = tid >> 3;   // 0..31
    const int skc  = tid & 7;
    const bf16_t* kb = K + ((size_t)bh * 2048) * 64;
    const bf16_t* vb = Vt + ((size_t)bh * 64) * 2048;
    bf16_t* pw = Ps[wave];

#pragma unroll 1
    for (int kt = 0; kt < 32; ++kt) {
        __syncthreads();
        // stage K tile [64][64] and V^T tile [64 d][64 key] into padded LDS
#pragma unroll
        for (int rr = 0; rr < 2; ++rr) {
            int row = srow + rr * 32;
            *(uint4*)(Ks + row * KP + skc * 8) =
                *(const uint4*)(kb + ((size_t)(kt * 64 + row)) * 64 + skc * 8);
            *(uint4*)(Vs + row * KP + skc * 8) =
                *(const uint4*)(vb + (size_t)row * 2048 + kt * 64 + skc * 8);
        }
        __syncthreads();

        // S = Qc * K^T  (per wave: 16 q x 64 keys)
        floatx4 s[4];
#pragma unroll
        for (int sub = 0; sub < 4; ++sub) {
            bf16x8 kf0 = *(const bf16x8*)(Ks + (sub * 16 + c) * KP + quad * 8);
            bf16x8 kf1 = *(const bf16x8*)(Ks + (sub * 16 + c) * KP + 32 + quad * 8);
            floatx4 t = (floatx4)0.0f;
            t = __builtin_amdgcn_mfma_f32_16x16x32_bf16(qf0, kf0, t, 0, 0, 0);
            t = __builtin_amdgcn_mfma_f32_16x16x32_bf16(qf1, kf1, t, 0, 0, 0);
            s[sub] = t;
        }

        // online softmax: rows live at quad*4+r, cols at lane&15 (+16*sub)
        float al[4];
#pragma unroll
        for (int r = 0; r < 4; r++) {
            float mx = fmaxf(fmaxf(s[0][r], s[1][r]), fmaxf(s[2][r], s[3][r]));
#pragma unroll
            for (int d = 1; d < 16; d <<= 1) mx = fmaxf(mx, __shfl_xor(mx, d, 64));
            float mnew = fmaxf(mrow[r], mx);
            al[r] = __expf(mrow[r] - mnew);
            float sum = 0.0f;
#pragma unroll
            for (int sub = 0; sub < 4; ++sub) {
                float p = __expf(s[sub][r] - mnew);
                s[sub][r] = p;
                sum += p;
            }
#pragma unroll
            for (int d = 1; d < 16; d <<= 1) sum += __shfl_xor(sum, d, 64);
            lrow[r] = lrow[r] * al[r] + sum;
            mrow[r] = mnew;
        }
        // rescale O accumulators
#pragma unroll
        for (int i = 0; i < 4; i++)
#pragma unroll
            for (int r = 0; r < 4; r++) o[i][r] *= al[r];

        // P -> LDS (C-layout write), then read back as A-operand
#pragma unroll
        for (int sub = 0; sub < 4; ++sub)
#pragma unroll
            for (int r = 0; r < 4; r++)
                pw[(quad * 4 + r) * KP + sub * 16 + c] = (bf16_t)s[sub][r];
        __syncthreads();

        // O += P * V   (A = P [16q x 64key], B = V [64key x 64d] read from Vt)
#pragma unroll
        for (int ks = 0; ks < 2; ++ks) {
            bf16x8 pf = *(const bf16x8*)(pw + c * KP + ks * 32 + quad * 8);
#pragma unroll
            for (int sub = 0; sub < 4; ++sub) {
                bf16x8 vf = *(const bf16x8*)(Vs + (sub * 16 + c) * KP + ks * 32 + quad * 8);
                o[sub] = __builtin_amdgcn_mfma_f32_16x16x32_bf16(pf, vf, o[sub], 0, 0, 0);
            }
        }
    }

    // epilogue: out[b][n][h*64 + d] = o / l
    int n0 = qt * 64 + wave * 16 + quad * 4;
    float* ob = Out + (size_t)b * 2048 * 512 + (size_t)h * 64;
#pragma unroll
    for (int r = 0; r < 4; r++) {
        float inv = 1.0f / lrow[r];
        float* orow = ob + (size_t)(n0 + r) * 512;
#pragma unroll
        for (int sub = 0; sub < 4; ++sub)
            orow[sub * 16 + c] = o[sub][r] * inv;
    }
}

// -------------------- launch --------------------
extern "C" void kernel_launch(void* const* d_in, const int* in_sizes, int n_in,
                              void* d_out, int out_size, void* d_ws, size_t ws_size,
                              hipStream_t stream) {
    const float* x = (const float*)d_in[0];   // [4,2048,512]
    const float* w = (const float*)d_in[1];   // [1536,512]
    float* out = (float*)d_out;               // [4,2048,512]

    char* ws = (char*)d_ws;
    bf16_t* xb = (bf16_t*)(ws);                       //  8 MB
    bf16_t* wb = (bf16_t*)(ws + 8388608);             //  1.5 MB
    bf16_t* q  = (bf16_t*)(ws + 9961472);             //  8 MB
    bf16_t* k  = (bf16_t*)(ws + 18350080);            //  8 MB
    bf16_t* vt = (bf16_t*)(ws + 26738688);            //  8 MB (end 33.5 MB)

    convert_kernel<<<4096, 256, 0, stream>>>(x, xb, 1048576);   // 4,194,304 / 4
    convert_kernel<<<768, 256, 0, stream>>>(w, wb, 196608);     //   786,432 / 4
    qkv_gemm<<<dim3(64, 12), 256, 0, stream>>>(xb, wb, q, k, vt);
    flash_attn<<<dim3(32, 32), 256, 0, stream>>>(q, k, vt, out);
}